// Round 1
// baseline (2514.542 us; speedup 1.0000x reference)
//
#include <hip/hip_runtime.h>
#include <stdint.h>

#define BATCH  4
#define SQ     2048
#define DMODEL 512
#define NH     8
#define DK     64

// ---------------- threefry2x32 (JAX-compatible, 20 rounds) ----------------
__device__ __forceinline__ void tf2x32(uint32_t k0, uint32_t k1,
                                       uint32_t x0, uint32_t x1,
                                       uint32_t &o0, uint32_t &o1) {
  const uint32_t ks2 = k0 ^ k1 ^ 0x1BD11BDAu;
  x0 += k0; x1 += k1;
#define TFR(d) { x0 += x1; x1 = (x1 << (d)) | (x1 >> (32 - (d))); x1 ^= x0; }
  TFR(13) TFR(15) TFR(26) TFR(6)
  x0 += k1; x1 += ks2 + 1u;
  TFR(17) TFR(29) TFR(16) TFR(24)
  x0 += ks2; x1 += k0 + 2u;
  TFR(13) TFR(15) TFR(26) TFR(6)
  x0 += k0; x1 += k1 + 3u;
  TFR(17) TFR(29) TFR(16) TFR(24)
  x0 += k1; x1 += ks2 + 4u;
  TFR(13) TFR(15) TFR(26) TFR(6)
  x0 += ks2; x1 += k0 + 5u;
#undef TFR
  o0 = x0; o1 = x1;
}

__device__ __forceinline__ float u01(uint32_t bits) {
  return __uint_as_float((bits >> 9) | 0x3f800000u) - 1.0f;
}

// Each thread fills one 32-bit word of each mask (32 consecutive flat indices).
// Partitionable threefry: bits[i] = o0 ^ o1 of tf(key, (0, i)).
__global__ __launch_bounds__(256) void mask_kernel(uint32_t *__restrict__ sp,
                                                   uint32_t *__restrict__ dp) {
  uint32_t w = blockIdx.x * 256u + threadIdx.x;
  uint32_t s0, s1, d0, d1;
  tf2x32(0u, 42u, 0u, 1u, s0, s1);  // fold_in(key(42), 1) -> sparsity key
  tf2x32(0u, 42u, 0u, 2u, d0, d1);  // fold_in(key(42), 2) -> dropout key
  uint32_t base = w * 32u;
  uint32_t sw = 0u, dw = 0u;
#pragma unroll 4
  for (int t = 0; t < 32; ++t) {
    uint32_t i = base + (uint32_t)t;
    uint32_t a0, a1;
    tf2x32(s0, s1, 0u, i, a0, a1);
    if (u01(a0 ^ a1) > 0.5f) sw |= (1u << t);
    tf2x32(d0, d1, 0u, i, a0, a1);
    if (u01(a0 ^ a1) >= 0.1f) dw |= (1u << t);
  }
  sp[w] = sw;
  dp[w] = dw;
}

// ---------------- fp32 tiled GEMM: Y[M,512] = X[M,512] @ W[512,512]^T + b ----
#define BM 64
#define BN 64
#define BK 32
__global__ __launch_bounds__(256) void proj_gemm(const float *__restrict__ X,
                                                 const float *__restrict__ W,
                                                 const float *__restrict__ bias,
                                                 float *__restrict__ Y) {
  __shared__ __align__(16) float Xs[BK][BM + 4];
  __shared__ __align__(16) float Ws[BK][BN + 4];
  const int bm = blockIdx.y * BM;
  const int bn = blockIdx.x * BN;
  const int tid = threadIdx.x;
  const int tx = tid & 15, ty = tid >> 4;
  float acc[4][4] = {};
  const int kk = tid & 31;
  const int r0 = tid >> 5;  // 0..7
  for (int k0 = 0; k0 < DMODEL; k0 += BK) {
#pragma unroll
    for (int p = 0; p < 8; ++p) {
      int r = r0 + p * 8;
      Xs[kk][r] = X[(size_t)(bm + r) * DMODEL + k0 + kk];
      Ws[kk][r] = W[(size_t)(bn + r) * DMODEL + k0 + kk];
    }
    __syncthreads();
#pragma unroll
    for (int k = 0; k < BK; ++k) {
      float4 a = *reinterpret_cast<const float4 *>(&Xs[k][ty * 4]);
      float4 b = *reinterpret_cast<const float4 *>(&Ws[k][tx * 4]);
      float av[4] = {a.x, a.y, a.z, a.w};
      float bv[4] = {b.x, b.y, b.z, b.w};
#pragma unroll
      for (int i = 0; i < 4; ++i)
#pragma unroll
        for (int j = 0; j < 4; ++j) acc[i][j] += av[i] * bv[j];
    }
    __syncthreads();
  }
#pragma unroll
  for (int i = 0; i < 4; ++i) {
    const int m = bm + ty * 4 + i;
#pragma unroll
    for (int j = 0; j < 4; ++j) {
      const int n = bn + tx * 4 + j;
      Y[(size_t)m * DMODEL + n] = acc[i][j] + bias[n];
    }
  }
}

// ---------------- attention: 1 thread = 1 query row -------------------------
__global__ __launch_bounds__(128) void attn_kernel(
    const float *__restrict__ qp, const float *__restrict__ kp,
    const float *__restrict__ vp, const uint32_t *__restrict__ spbits,
    const uint32_t *__restrict__ dpbits, float *__restrict__ xa) {
  __shared__ __align__(16) float Ks[64][DK];
  __shared__ __align__(16) float Vs[64][DK];
  const int b = blockIdx.z, h = blockIdx.y;
  const int qi = blockIdx.x * 128 + threadIdx.x;
  const int tid = threadIdx.x;

  float q[DK];
  {
    const float *qrow = qp + ((size_t)(b * SQ + qi)) * DMODEL + h * DK;
#pragma unroll
    for (int d = 0; d < DK; d += 4) {
      float4 t = *reinterpret_cast<const float4 *>(qrow + d);
      q[d] = t.x * 0.125f; q[d + 1] = t.y * 0.125f;
      q[d + 2] = t.z * 0.125f; q[d + 3] = t.w * 0.125f;
    }
  }
  float acc[DK];
#pragma unroll
  for (int d = 0; d < DK; ++d) acc[d] = 0.f;
  float l = 0.f;

  // word offset of this row's mask bits: row_flat * (SQ/32)
  const size_t mrow = ((size_t)((b * NH + h) * SQ) + qi) * (SQ / 32);

  const int v4 = tid & 15;   // float4 index within a 64-float row
  const int r0 = tid >> 4;   // 8 rows per pass

#pragma unroll 1
  for (int t0 = 0; t0 < SQ; t0 += 64) {
    __syncthreads();
#pragma unroll
    for (int p = 0; p < 8; ++p) {
      const int r = r0 + p * 8;
      const float *krow = kp + ((size_t)(b * SQ + t0 + r)) * DMODEL + h * DK;
      const float *vrow = vp + ((size_t)(b * SQ + t0 + r)) * DMODEL + h * DK;
      *reinterpret_cast<float4 *>(&Ks[r][v4 * 4]) =
          *reinterpret_cast<const float4 *>(krow + v4 * 4);
      *reinterpret_cast<float4 *>(&Vs[r][v4 * 4]) =
          *reinterpret_cast<const float4 *>(vrow + v4 * 4);
    }
    __syncthreads();

    const uint32_t sw0 = spbits[mrow + (t0 >> 5)];
    const uint32_t sw1 = spbits[mrow + (t0 >> 5) + 1];
    const uint32_t dw0 = dpbits[mrow + (t0 >> 5)];
    const uint32_t dw1 = dpbits[mrow + (t0 >> 5) + 1];
    const uint64_t swm = ((uint64_t)sw1 << 32) | sw0;
    const uint64_t dwm = ((uint64_t)dw1 << 32) | dw0;

#pragma unroll 1
    for (int kkk = 0; kkk < 64; kkk += 4) {
      float s[4] = {0.f, 0.f, 0.f, 0.f};
#pragma unroll
      for (int d4 = 0; d4 < DK; d4 += 4) {
#pragma unroll
        for (int j = 0; j < 4; ++j) {
          float4 kv = *reinterpret_cast<const float4 *>(&Ks[kkk + j][d4]);
          s[j] += q[d4] * kv.x + q[d4 + 1] * kv.y + q[d4 + 2] * kv.z +
                  q[d4 + 3] * kv.w;
        }
      }
      float p[4];
#pragma unroll
      for (int j = 0; j < 4; ++j) {
        const bool keep_s = (swm >> (kkk + j)) & 1ull;
        p[j] = keep_s ? __expf(s[j]) : 0.f;
        l += p[j];
        const bool keep_d = (dwm >> (kkk + j)) & 1ull;
        p[j] = keep_d ? p[j] * (1.0f / 0.9f) : 0.f;
      }
#pragma unroll
      for (int d = 0; d < DK; d += 4) {
        float4 v0 = *reinterpret_cast<const float4 *>(&Vs[kkk][d]);
        float4 v1 = *reinterpret_cast<const float4 *>(&Vs[kkk + 1][d]);
        float4 v2 = *reinterpret_cast<const float4 *>(&Vs[kkk + 2][d]);
        float4 v3 = *reinterpret_cast<const float4 *>(&Vs[kkk + 3][d]);
        acc[d]     += p[0] * v0.x + p[1] * v1.x + p[2] * v2.x + p[3] * v3.x;
        acc[d + 1] += p[0] * v0.y + p[1] * v1.y + p[2] * v2.y + p[3] * v3.y;
        acc[d + 2] += p[0] * v0.z + p[1] * v1.z + p[2] * v2.z + p[3] * v3.z;
        acc[d + 3] += p[0] * v0.w + p[1] * v1.w + p[2] * v2.w + p[3] * v3.w;
      }
    }
  }

  const float inv = 1.0f / l;
  float *orow = xa + ((size_t)(b * SQ + qi)) * DMODEL + h * DK;
#pragma unroll
  for (int d = 0; d < DK; d += 4) {
    float4 t;
    t.x = acc[d] * inv; t.y = acc[d + 1] * inv;
    t.z = acc[d + 2] * inv; t.w = acc[d + 3] * inv;
    *reinterpret_cast<float4 *>(orow + d) = t;
  }
}

// ---------------------------------------------------------------------------
extern "C" void kernel_launch(void *const *d_in, const int *in_sizes, int n_in,
                              void *d_out, int out_size, void *d_ws,
                              size_t ws_size, hipStream_t stream) {
  (void)in_sizes; (void)n_in; (void)out_size;
  const float *query = (const float *)d_in[0];
  const float *key_  = (const float *)d_in[1];
  const float *value = (const float *)d_in[2];
  const float *Wq = (const float *)d_in[3];
  const float *bq = (const float *)d_in[4];
  const float *Wk = (const float *)d_in[5];
  const float *bk = (const float *)d_in[6];
  const float *Wv = (const float *)d_in[7];
  const float *bv = (const float *)d_in[8];
  const float *Wo = (const float *)d_in[9];
  const float *bo = (const float *)d_in[10];
  float *out = (float *)d_out;

  const size_t MB16 = (size_t)16 << 20;
  if (ws_size < 6 * MB16) return;  // diagnostic: output stays zero -> absmax 0.2236

  char *ws = (char *)d_ws;
  float *qp = (float *)(ws);
  float *kp = (float *)(ws + 1 * MB16);
  float *vp = (float *)(ws + 2 * MB16);
  float *xa = (float *)(ws + 3 * MB16);
  uint32_t *spb = (uint32_t *)(ws + 4 * MB16);
  uint32_t *dpb = (uint32_t *)(ws + 5 * MB16);

  // masks: 2^27 elements / 32 bits per word / 256 threads = 16384 blocks
  mask_kernel<<<16384, 256, 0, stream>>>(spb, dpb);

  dim3 gg(DMODEL / BN, (BATCH * SQ) / BM);
  proj_gemm<<<gg, 256, 0, stream>>>(query, Wq, bq, qp);
  proj_gemm<<<gg, 256, 0, stream>>>(key_, Wk, bk, kp);
  proj_gemm<<<gg, 256, 0, stream>>>(value, Wv, bv, vp);

  attn_kernel<<<dim3(SQ / 128, NH, BATCH), 128, 0, stream>>>(qp, kp, vp, spb,
                                                             dpb, xa);

  proj_gemm<<<gg, 256, 0, stream>>>(xa, Wo, bo, out);
}

// Round 2
// 872.029 us; speedup vs baseline: 2.8836x; 2.8836x over previous
//
#include <hip/hip_runtime.h>
#include <stdint.h>

#define BATCH  4
#define SQ     2048
#define DMODEL 512
#define NH     8
#define DK     64

typedef __attribute__((ext_vector_type(8))) short short8;
typedef __attribute__((ext_vector_type(4))) float f32x4;

// ---------------- threefry2x32 (JAX-compatible, 20 rounds) ----------------
__device__ __forceinline__ void tf2x32(uint32_t k0, uint32_t k1,
                                       uint32_t x0, uint32_t x1,
                                       uint32_t &o0, uint32_t &o1) {
  const uint32_t ks2 = k0 ^ k1 ^ 0x1BD11BDAu;
  x0 += k0; x1 += k1;
#define TFR(d) { x0 += x1; x1 = (x1 << (d)) | (x1 >> (32 - (d))); x1 ^= x0; }
  TFR(13) TFR(15) TFR(26) TFR(6)
  x0 += k1; x1 += ks2 + 1u;
  TFR(17) TFR(29) TFR(16) TFR(24)
  x0 += ks2; x1 += k0 + 2u;
  TFR(13) TFR(15) TFR(26) TFR(6)
  x0 += k0; x1 += k1 + 3u;
  TFR(17) TFR(29) TFR(16) TFR(24)
  x0 += k1; x1 += ks2 + 4u;
  TFR(13) TFR(15) TFR(26) TFR(6)
  x0 += ks2; x1 += k0 + 5u;
#undef TFR
  o0 = x0; o1 = x1;
}

__device__ __forceinline__ float u01(uint32_t bits) {
  return __uint_as_float((bits >> 9) | 0x3f800000u) - 1.0f;
}

__device__ __forceinline__ ushort f2bf_rne(float f) {
  uint32_t u = __float_as_uint(f);
  return (ushort)((u + 0x7fffu + ((u >> 16) & 1u)) >> 16);
}

__global__ __launch_bounds__(256) void mask_kernel(uint32_t *__restrict__ sp,
                                                   uint32_t *__restrict__ dp) {
  uint32_t w = blockIdx.x * 256u + threadIdx.x;
  uint32_t s0, s1, d0, d1;
  tf2x32(0u, 42u, 0u, 1u, s0, s1);
  tf2x32(0u, 42u, 0u, 2u, d0, d1);
  uint32_t base = w * 32u;
  uint32_t sw = 0u, dw = 0u;
#pragma unroll 4
  for (int t = 0; t < 32; ++t) {
    uint32_t i = base + (uint32_t)t;
    uint32_t a0, a1;
    tf2x32(s0, s1, 0u, i, a0, a1);
    if (u01(a0 ^ a1) > 0.5f) sw |= (1u << t);
    tf2x32(d0, d1, 0u, i, a0, a1);
    if (u01(a0 ^ a1) >= 0.1f) dw |= (1u << t);
  }
  sp[w] = sw;
  dp[w] = dw;
}

// ---------------- fp32 tiled GEMM: Y[M,512] = X[M,512] @ W[512,512]^T + b ----
// MODE 0: fp32 row-major out. MODE 1: bf16 row-major out.
// MODE 2: bf16 transposed out  vpt[(b*512 + n)*2048 + s]  (per-head V^T).
#define BM 64
#define BN 64
#define BK 32
template <int MODE>
__global__ __launch_bounds__(256) void proj_gemm_t(const float *__restrict__ X,
                                                   const float *__restrict__ W,
                                                   const float *__restrict__ bias,
                                                   void *__restrict__ Yv) {
  __shared__ __align__(16) uint8_t smem[17408];
  float (*Xs)[BM + 4] = (float (*)[BM + 4])smem;            // 32 x 68 x 4 = 8704 B
  float (*Ws)[BN + 4] = (float (*)[BN + 4])(smem + 8704);   // 32 x 68 x 4 = 8704 B
  const int bm = blockIdx.y * BM;
  const int bn = blockIdx.x * BN;
  const int tid = threadIdx.x;
  const int tx = tid & 15, ty = tid >> 4;
  float acc[4][4] = {};
  const int kk = tid & 31;
  const int r0 = tid >> 5;
  for (int k0 = 0; k0 < DMODEL; k0 += BK) {
#pragma unroll
    for (int p = 0; p < 8; ++p) {
      int r = r0 + p * 8;
      Xs[kk][r] = X[(size_t)(bm + r) * DMODEL + k0 + kk];
      Ws[kk][r] = W[(size_t)(bn + r) * DMODEL + k0 + kk];
    }
    __syncthreads();
#pragma unroll
    for (int k = 0; k < BK; ++k) {
      float4 a = *reinterpret_cast<const float4 *>(&Xs[k][ty * 4]);
      float4 b = *reinterpret_cast<const float4 *>(&Ws[k][tx * 4]);
      float av[4] = {a.x, a.y, a.z, a.w};
      float bv[4] = {b.x, b.y, b.z, b.w};
#pragma unroll
      for (int i = 0; i < 4; ++i)
#pragma unroll
        for (int j = 0; j < 4; ++j) acc[i][j] += av[i] * bv[j];
    }
    __syncthreads();
  }

  if (MODE == 0) {
    float *Y = (float *)Yv;
#pragma unroll
    for (int i = 0; i < 4; ++i) {
      const int m = bm + ty * 4 + i;
#pragma unroll
      for (int j = 0; j < 4; ++j) {
        const int n = bn + tx * 4 + j;
        Y[(size_t)m * DMODEL + n] = acc[i][j] + bias[n];
      }
    }
  } else if (MODE == 1) {
    ushort *Y = (ushort *)Yv;
#pragma unroll
    for (int i = 0; i < 4; ++i) {
      const int m = bm + ty * 4 + i;
      uint32_t u0 = f2bf_rne(acc[i][0] + bias[bn + tx * 4 + 0]);
      uint32_t u1 = f2bf_rne(acc[i][1] + bias[bn + tx * 4 + 1]);
      uint32_t u2 = f2bf_rne(acc[i][2] + bias[bn + tx * 4 + 2]);
      uint32_t u3 = f2bf_rne(acc[i][3] + bias[bn + tx * 4 + 3]);
      uint2 pk;
      pk.x = u0 | (u1 << 16);
      pk.y = u2 | (u3 << 16);
      *(uint2 *)&Y[(size_t)m * DMODEL + bn + tx * 4] = pk;
    }
  } else {
    // transpose through LDS (reuse smem): T[64][72] ushort (stride 144B, 16B-aligned)
    ushort *T = (ushort *)smem;
#pragma unroll
    for (int i = 0; i < 4; ++i)
#pragma unroll
      for (int j = 0; j < 4; ++j) {
        const int nl = tx * 4 + j, ml = ty * 4 + i;
        T[nl * 72 + ml] = f2bf_rne(acc[i][j] + bias[bn + nl]);
      }
    __syncthreads();
    ushort *Y = (ushort *)Yv;
    const int row = tid >> 2, seg = tid & 3;  // 64 rows x 4 segs of 16
    uint4 a = *(uint4 *)&T[row * 72 + seg * 16];
    uint4 b2 = *(uint4 *)&T[row * 72 + seg * 16 + 8];
    const size_t gaddr =
        ((size_t)((bm >> 11) * 512 + bn + row)) * SQ + (bm & 2047) + seg * 16;
    *(uint4 *)&Y[gaddr] = a;
    *(uint4 *)&Y[gaddr + 8] = b2;
  }
}

// ---------------- MFMA attention ------------------------------------------
// Block: 64 q-rows (4 waves x 16), loops 64-key tiles. 16x16x32 bf16 MFMA.
// A-frag: row=l&15, k=(l>>4)*8+j.  B-frag: col=l&15, k=(l>>4)*8+j.
// D-frag: col=l&15, row=(l>>4)*4+reg.
__global__ __launch_bounds__(256, 4) void attn_mfma(
    const ushort *__restrict__ qp, const ushort *__restrict__ kp,
    const ushort *__restrict__ vpt, const uint32_t *__restrict__ spb,
    const uint32_t *__restrict__ dpb, float *__restrict__ xa) {
  __shared__ __align__(16) uint8_t lds[24576];
  uint8_t *Ks = lds;                 // [64 key][64 d] bf16, XOR-swizzled
  uint8_t *Vt = lds + 8192;          // [64 d][64 key] bf16, XOR-swizzled
  const int b = blockIdx.z, h = blockIdx.y;
  const int qb = blockIdx.x * 64;
  const int tid = threadIdx.x;
  const int w = tid >> 6, l = tid & 63;
  const int lr = l & 15, lq = l >> 4;
  uint8_t *Ps = lds + 16384 + w * 2048;  // per-wave [16 q][64 key] bf16, swizzled
  const int bh = b * NH + h;

  // Q fragments: 16 rows x 64 d per wave, in registers
  short8 qf[2];
  {
    const int qrow = qb + w * 16 + lr;
    const ushort *qrowp = qp + ((size_t)(b * SQ + qrow)) * DMODEL + h * DK;
    qf[0] = *(const short8 *)(qrowp + lq * 8);
    qf[1] = *(const short8 *)(qrowp + 32 + lq * 8);
  }
  f32x4 o[4];
  f32x4 lacc;
#pragma unroll
  for (int nd = 0; nd < 4; ++nd) o[nd] = (f32x4){0.f, 0.f, 0.f, 0.f};
  lacc = (f32x4){0.f, 0.f, 0.f, 0.f};

  for (int kv = 0; kv < SQ; kv += 64) {
    __syncthreads();
    {  // stage K and Vt tiles (swizzled)
      const int row = tid >> 2;            // 0..63
      const int c0 = (tid & 3) * 2;        // 0,2,4,6
      const int sw = (row & 7) << 4;
      const ushort *ksrc =
          kp + ((size_t)(b * SQ + kv + row)) * DMODEL + h * DK + c0 * 8;
      uint4 d0 = *(const uint4 *)ksrc;
      uint4 d1 = *(const uint4 *)(ksrc + 8);
      *(uint4 *)(Ks + ((row * 128 + c0 * 16) ^ sw)) = d0;
      *(uint4 *)(Ks + ((row * 128 + (c0 + 1) * 16) ^ sw)) = d1;
      const ushort *vsrc = vpt + ((size_t)(bh * DK + row)) * SQ + kv + c0 * 8;
      uint4 e0 = *(const uint4 *)vsrc;
      uint4 e1 = *(const uint4 *)(vsrc + 8);
      *(uint4 *)(Vt + ((row * 128 + c0 * 16) ^ sw)) = e0;
      *(uint4 *)(Vt + ((row * 128 + (c0 + 1) * 16) ^ sw)) = e1;
    }
    __syncthreads();

    // QK^T: scores for 16 q x 64 keys per wave
    f32x4 s[4];
#pragma unroll
    for (int ni = 0; ni < 4; ++ni) s[ni] = (f32x4){0.f, 0.f, 0.f, 0.f};
#pragma unroll
    for (int ni = 0; ni < 4; ++ni) {
      const int krow = ni * 16 + lr;
      const int sw = (krow & 7) << 4;
#pragma unroll
      for (int kf = 0; kf < 2; ++kf) {
        short8 kb =
            *(const short8 *)(Ks + ((krow * 128 + kf * 64 + lq * 16) ^ sw));
        s[ni] = __builtin_amdgcn_mfma_f32_16x16x32_bf16(qf[kf], kb, s[ni], 0, 0, 0);
      }
    }

    // masks for this tile: 4 rows x 2 words per mask
    const int wq = kv >> 5;
    const size_t mbase = ((size_t)bh * SQ + (qb + w * 16 + lq * 4)) * 64 + wq;
    uint2 swd[4], dwd[4];
#pragma unroll
    for (int r = 0; r < 4; ++r) {
      swd[r] = *(const uint2 *)(spb + mbase + (size_t)r * 64);
      dwd[r] = *(const uint2 *)(dpb + mbase + (size_t)r * 64);
    }

    // softmax numerator + dropout, write P to per-wave LDS
#pragma unroll
    for (int ni = 0; ni < 4; ++ni) {
      const int bpos = (ni & 1) * 16 + lr;
#pragma unroll
      for (int r = 0; r < 4; ++r) {
        const uint32_t sws = (ni < 2) ? swd[r].x : swd[r].y;
        const uint32_t dws = (ni < 2) ? dwd[r].x : dwd[r].y;
        float e = __expf(s[ni][r] * 0.125f);
        float p = ((sws >> bpos) & 1u) ? e : 0.0f;
        lacc[r] += p;
        float pd = ((dws >> bpos) & 1u) ? p * (1.0f / 0.9f) : 0.0f;
        const int prow = lq * 4 + r;
        *(ushort *)(Ps + ((prow * 128 + (ni * 16 + lr) * 2) ^ ((prow & 7) << 4))) =
            f2bf_rne(pd);
      }
    }

    // PV: out[16 q][64 d] += P(16x64) * V(64x64)
#pragma unroll
    for (int kf = 0; kf < 2; ++kf) {
      short8 pa = *(const short8 *)(Ps +
                                    ((lr * 128 + kf * 64 + lq * 16) ^ ((lr & 7) << 4)));
#pragma unroll
      for (int nd = 0; nd < 4; ++nd) {
        const int vrow = nd * 16 + lr;
        short8 vb = *(const short8 *)(Vt + ((vrow * 128 + kf * 64 + lq * 16) ^
                                            ((vrow & 7) << 4)));
        o[nd] = __builtin_amdgcn_mfma_f32_16x16x32_bf16(pa, vb, o[nd], 0, 0, 0);
      }
    }
  }

  // row sums -> normalize -> store
  float inv[4];
#pragma unroll
  for (int r = 0; r < 4; ++r) {
    float t = lacc[r];
    t += __shfl_xor(t, 1);
    t += __shfl_xor(t, 2);
    t += __shfl_xor(t, 4);
    t += __shfl_xor(t, 8);
    inv[r] = 1.0f / t;
  }
#pragma unroll
  for (int nd = 0; nd < 4; ++nd)
#pragma unroll
    for (int r = 0; r < 4; ++r) {
      const int qrow = qb + w * 16 + lq * 4 + r;
      xa[((size_t)(b * SQ + qrow)) * DMODEL + h * DK + nd * 16 + lr] =
          o[nd][r] * inv[r];
    }
}

// ---------------------------------------------------------------------------
extern "C" void kernel_launch(void *const *d_in, const int *in_sizes, int n_in,
                              void *d_out, int out_size, void *d_ws,
                              size_t ws_size, hipStream_t stream) {
  (void)in_sizes; (void)n_in; (void)out_size;
  const float *query = (const float *)d_in[0];
  const float *key_  = (const float *)d_in[1];
  const float *value = (const float *)d_in[2];
  const float *Wq = (const float *)d_in[3];
  const float *bq = (const float *)d_in[4];
  const float *Wk = (const float *)d_in[5];
  const float *bk = (const float *)d_in[6];
  const float *Wv = (const float *)d_in[7];
  const float *bv = (const float *)d_in[8];
  const float *Wo = (const float *)d_in[9];
  const float *bo = (const float *)d_in[10];
  float *out = (float *)d_out;

  const size_t MB = (size_t)1 << 20;
  if (ws_size < 72 * MB) return;

  char *ws = (char *)d_ws;
  ushort *qp  = (ushort *)(ws);            // 8 MB bf16 [B*S][512]
  ushort *kp  = (ushort *)(ws + 8 * MB);   // 8 MB bf16 [B*S][512]
  ushort *vpt = (ushort *)(ws + 16 * MB);  // 8 MB bf16 [B*512 n][2048 s]
  float  *xa  = (float *)(ws + 24 * MB);   // 16 MB fp32 [B*S][512]
  uint32_t *spb = (uint32_t *)(ws + 40 * MB);  // 16 MB
  uint32_t *dpb = (uint32_t *)(ws + 56 * MB);  // 16 MB

  mask_kernel<<<16384, 256, 0, stream>>>(spb, dpb);

  dim3 gg(DMODEL / BN, (BATCH * SQ) / BM);
  proj_gemm_t<1><<<gg, 256, 0, stream>>>(query, Wq, bq, (void *)qp);
  proj_gemm_t<1><<<gg, 256, 0, stream>>>(key_, Wk, bk, (void *)kp);
  proj_gemm_t<2><<<gg, 256, 0, stream>>>(value, Wv, bv, (void *)vpt);

  attn_mfma<<<dim3(SQ / 64, NH, BATCH), 256, 0, stream>>>(qp, kp, vpt, spb,
                                                          dpb, xa);

  proj_gemm_t<0><<<gg, 256, 0, stream>>>(xa, Wo, bo, out);
}

// Round 3
// 793.964 us; speedup vs baseline: 3.1671x; 1.0983x over previous
//
#include <hip/hip_runtime.h>
#include <stdint.h>

#define BATCH  4
#define SQ     2048
#define DMODEL 512
#define NH     8
#define DK     64

typedef __attribute__((ext_vector_type(8))) short short8;
typedef __attribute__((ext_vector_type(4))) float f32x4;

// ---------------- threefry2x32 (JAX-compatible, 20 rounds) ----------------
// Compile-time variant for key derivation (fold_in of constants).
struct TFK { uint32_t a, b; };
constexpr uint32_t rotl_ce(uint32_t x, int d) {
  return (x << d) | (x >> (32 - d));
}
constexpr TFK tf_ce(uint32_t k0, uint32_t k1, uint32_t x0, uint32_t x1) {
  const uint32_t ks[3] = {k0, k1, k0 ^ k1 ^ 0x1BD11BDAu};
  const int rot[2][4] = {{13, 15, 26, 6}, {17, 29, 16, 24}};
  x0 += k0; x1 += k1;
  for (int c = 0; c < 5; ++c) {
    for (int j = 0; j < 4; ++j) {
      x0 += x1; x1 = rotl_ce(x1, rot[c & 1][j]); x1 ^= x0;
    }
    x0 += ks[(c + 1) % 3];
    x1 += ks[(c + 2) % 3] + (uint32_t)(c + 1);
  }
  return TFK{x0, x1};
}
constexpr TFK SPK = tf_ce(0u, 42u, 0u, 1u);  // fold_in(key(42), 1)
constexpr TFK DPK = tf_ce(0u, 42u, 0u, 2u);  // fold_in(key(42), 2)

// Device hash with compile-time keys: bits(i) = o0 ^ o1 of tf(key, (0, i)).
template <uint32_t K0, uint32_t K1>
__device__ __forceinline__ uint32_t tf_bits(uint32_t ctr) {
  constexpr uint32_t KS2 = K0 ^ K1 ^ 0x1BD11BDAu;
  uint32_t x0 = K0;
  uint32_t x1 = K1 + ctr;
#define RND(d) { x0 += x1; x1 = __builtin_amdgcn_alignbit(x1, x1, 32 - (d)); x1 ^= x0; }
  RND(13) RND(15) RND(26) RND(6)
  x0 += K1; x1 += KS2 + 1u;
  RND(17) RND(29) RND(16) RND(24)
  x0 += KS2; x1 += K0 + 2u;
  RND(13) RND(15) RND(26) RND(6)
  x0 += K0; x1 += K1 + 3u;
  RND(17) RND(29) RND(16) RND(24)
  x0 += K1; x1 += KS2 + 4u;
  RND(13) RND(15) RND(26) RND(6)
  x0 += KS2; x1 += K0 + 5u;
#undef RND
  return x0 ^ x1;
}

// keep_sparse: u01 > 0.5  <=> bits >= 0x80000200
// keep_drop:   u01 >= 0.1f <=> (bits>>9) >= ceil(0.1f * 2^23) = 0xCCCCD
#define SP_THR 0x80000200u
#define DP_THR 0x1999A200u

__device__ __forceinline__ ushort f2bf_rne(float f) {
  uint32_t u = __float_as_uint(f);
  return (ushort)((u + 0x7fffu + ((u >> 16) & 1u)) >> 16);
}

// ---------------- fp32 tiled GEMM: Y[M,512] = X[M,512] @ W[512,512]^T + b ----
#define BM 64
#define BN 64
#define BK 32
template <int MODE>
__global__ __launch_bounds__(256) void proj_gemm_t(const float *__restrict__ X,
                                                   const float *__restrict__ W,
                                                   const float *__restrict__ bias,
                                                   void *__restrict__ Yv) {
  __shared__ __align__(16) uint8_t smem[17408];
  float (*Xs)[BM + 4] = (float (*)[BM + 4])smem;
  float (*Ws)[BN + 4] = (float (*)[BN + 4])(smem + 8704);
  const int bm = blockIdx.y * BM;
  const int bn = blockIdx.x * BN;
  const int tid = threadIdx.x;
  const int tx = tid & 15, ty = tid >> 4;
  float acc[4][4] = {};
  const int kk = tid & 31;
  const int r0 = tid >> 5;
  for (int k0 = 0; k0 < DMODEL; k0 += BK) {
#pragma unroll
    for (int p = 0; p < 8; ++p) {
      int r = r0 + p * 8;
      Xs[kk][r] = X[(size_t)(bm + r) * DMODEL + k0 + kk];
      Ws[kk][r] = W[(size_t)(bn + r) * DMODEL + k0 + kk];
    }
    __syncthreads();
#pragma unroll
    for (int k = 0; k < BK; ++k) {
      float4 a = *reinterpret_cast<const float4 *>(&Xs[k][ty * 4]);
      float4 b = *reinterpret_cast<const float4 *>(&Ws[k][tx * 4]);
      float av[4] = {a.x, a.y, a.z, a.w};
      float bv[4] = {b.x, b.y, b.z, b.w};
#pragma unroll
      for (int i = 0; i < 4; ++i)
#pragma unroll
        for (int j = 0; j < 4; ++j) acc[i][j] += av[i] * bv[j];
    }
    __syncthreads();
  }

  if (MODE == 0) {
    float *Y = (float *)Yv;
#pragma unroll
    for (int i = 0; i < 4; ++i) {
      const int m = bm + ty * 4 + i;
#pragma unroll
      for (int j = 0; j < 4; ++j) {
        const int n = bn + tx * 4 + j;
        Y[(size_t)m * DMODEL + n] = acc[i][j] + bias[n];
      }
    }
  } else if (MODE == 1) {
    ushort *Y = (ushort *)Yv;
#pragma unroll
    for (int i = 0; i < 4; ++i) {
      const int m = bm + ty * 4 + i;
      uint32_t u0 = f2bf_rne(acc[i][0] + bias[bn + tx * 4 + 0]);
      uint32_t u1 = f2bf_rne(acc[i][1] + bias[bn + tx * 4 + 1]);
      uint32_t u2 = f2bf_rne(acc[i][2] + bias[bn + tx * 4 + 2]);
      uint32_t u3 = f2bf_rne(acc[i][3] + bias[bn + tx * 4 + 3]);
      uint2 pk;
      pk.x = u0 | (u1 << 16);
      pk.y = u2 | (u3 << 16);
      *(uint2 *)&Y[(size_t)m * DMODEL + bn + tx * 4] = pk;
    }
  } else {
    ushort *T = (ushort *)smem;
#pragma unroll
    for (int i = 0; i < 4; ++i)
#pragma unroll
      for (int j = 0; j < 4; ++j) {
        const int nl = tx * 4 + j, ml = ty * 4 + i;
        T[nl * 72 + ml] = f2bf_rne(acc[i][j] + bias[bn + nl]);
      }
    __syncthreads();
    ushort *Y = (ushort *)Yv;
    const int row = tid >> 2, seg = tid & 3;
    uint4 a = *(uint4 *)&T[row * 72 + seg * 16];
    uint4 b2 = *(uint4 *)&T[row * 72 + seg * 16 + 8];
    const size_t gaddr =
        ((size_t)((bm >> 11) * 512 + bn + row)) * SQ + (bm & 2047) + seg * 16;
    *(uint4 *)&Y[gaddr] = a;
    *(uint4 *)&Y[gaddr + 8] = b2;
  }
}

// ---------------- MFMA attention with fused mask generation -----------------
// Block: 64 q-rows (4 waves x 16), loops 64-key tiles. 16x16x32 bf16 MFMA.
// Each lane computes the threefry mask bits for exactly the 16 score elements
// it owns in the D-fragment layout (col=l&15, row=(l>>4)*4+reg).
__global__ __launch_bounds__(256, 2) void attn_mfma(
    const ushort *__restrict__ qp, const ushort *__restrict__ kp,
    const ushort *__restrict__ vpt, float *__restrict__ xa) {
  __shared__ __align__(16) uint8_t lds[24576];
  uint8_t *Ks = lds;                 // [64 key][64 d] bf16, XOR-swizzled
  uint8_t *Vt = lds + 8192;          // [64 d][64 key] bf16, XOR-swizzled
  const int b = blockIdx.z, h = blockIdx.y;
  const int qb = blockIdx.x * 64;
  const int tid = threadIdx.x;
  const int w = tid >> 6, l = tid & 63;
  const int lr = l & 15, lq = l >> 4;
  uint8_t *Ps = lds + 16384 + w * 2048;  // per-wave [16 q][64 key] bf16, swizzled
  const int bh = b * NH + h;

  short8 qf[2];
  {
    const int qrow = qb + w * 16 + lr;
    const ushort *qrowp = qp + ((size_t)(b * SQ + qrow)) * DMODEL + h * DK;
    qf[0] = *(const short8 *)(qrowp + lq * 8);
    qf[1] = *(const short8 *)(qrowp + 32 + lq * 8);
  }
  f32x4 o[4];
  f32x4 lacc;
#pragma unroll
  for (int nd = 0; nd < 4; ++nd) o[nd] = (f32x4){0.f, 0.f, 0.f, 0.f};
  lacc = (f32x4){0.f, 0.f, 0.f, 0.f};

  // flat mask counter base per owned q-row: ((bh*2048 + q) << 11)
  uint32_t rowflat[4];
#pragma unroll
  for (int r = 0; r < 4; ++r)
    rowflat[r] = ((uint32_t)(bh * SQ + qb + w * 16 + lq * 4 + r)) << 11;

  for (int kv = 0; kv < SQ; kv += 64) {
    __syncthreads();
    {  // stage K and Vt tiles (swizzled)
      const int row = tid >> 2;
      const int c0 = (tid & 3) * 2;
      const int sw = (row & 7) << 4;
      const ushort *ksrc =
          kp + ((size_t)(b * SQ + kv + row)) * DMODEL + h * DK + c0 * 8;
      uint4 d0 = *(const uint4 *)ksrc;
      uint4 d1 = *(const uint4 *)(ksrc + 8);
      *(uint4 *)(Ks + ((row * 128 + c0 * 16) ^ sw)) = d0;
      *(uint4 *)(Ks + ((row * 128 + (c0 + 1) * 16) ^ sw)) = d1;
      const ushort *vsrc = vpt + ((size_t)(bh * DK + row)) * SQ + kv + c0 * 8;
      uint4 e0 = *(const uint4 *)vsrc;
      uint4 e1 = *(const uint4 *)(vsrc + 8);
      *(uint4 *)(Vt + ((row * 128 + c0 * 16) ^ sw)) = e0;
      *(uint4 *)(Vt + ((row * 128 + (c0 + 1) * 16) ^ sw)) = e1;
    }
    __syncthreads();

    // QK^T: scores for 16 q x 64 keys per wave
    f32x4 s[4];
#pragma unroll
    for (int ni = 0; ni < 4; ++ni) s[ni] = (f32x4){0.f, 0.f, 0.f, 0.f};
#pragma unroll
    for (int ni = 0; ni < 4; ++ni) {
      const int krow = ni * 16 + lr;
      const int sw = (krow & 7) << 4;
#pragma unroll
      for (int kf = 0; kf < 2; ++kf) {
        short8 kb =
            *(const short8 *)(Ks + ((krow * 128 + kf * 64 + lq * 16) ^ sw));
        s[ni] = __builtin_amdgcn_mfma_f32_16x16x32_bf16(qf[kf], kb, s[ni], 0, 0, 0);
      }
    }

    // fused threefry masks + softmax numerator + dropout -> P in LDS
#pragma unroll
    for (int ni = 0; ni < 4; ++ni) {
#pragma unroll
      for (int r = 0; r < 4; ++r) {
        const uint32_t ctr = rowflat[r] + (uint32_t)(kv + ni * 16 + lr);
        const bool keep_s = tf_bits<SPK.a, SPK.b>(ctr) >= SP_THR;
        const bool keep_d = tf_bits<DPK.a, DPK.b>(ctr) >= DP_THR;
        float e = __expf(s[ni][r] * 0.125f);
        float p = keep_s ? e : 0.0f;
        lacc[r] += p;
        float pd = keep_d ? p * (1.0f / 0.9f) : 0.0f;
        const int prow = lq * 4 + r;
        *(ushort *)(Ps + ((prow * 128 + (ni * 16 + lr) * 2) ^ ((prow & 7) << 4))) =
            f2bf_rne(pd);
      }
    }

    // PV: out[16 q][64 d] += P(16x64) * V(64x64)
#pragma unroll
    for (int kf = 0; kf < 2; ++kf) {
      short8 pa = *(const short8 *)(Ps +
                                    ((lr * 128 + kf * 64 + lq * 16) ^ ((lr & 7) << 4)));
#pragma unroll
      for (int nd = 0; nd < 4; ++nd) {
        const int vrow = nd * 16 + lr;
        short8 vb = *(const short8 *)(Vt + ((vrow * 128 + kf * 64 + lq * 16) ^
                                            ((vrow & 7) << 4)));
        o[nd] = __builtin_amdgcn_mfma_f32_16x16x32_bf16(pa, vb, o[nd], 0, 0, 0);
      }
    }
  }

  float inv[4];
#pragma unroll
  for (int r = 0; r < 4; ++r) {
    float t = lacc[r];
    t += __shfl_xor(t, 1);
    t += __shfl_xor(t, 2);
    t += __shfl_xor(t, 4);
    t += __shfl_xor(t, 8);
    inv[r] = 1.0f / t;
  }
#pragma unroll
  for (int nd = 0; nd < 4; ++nd)
#pragma unroll
    for (int r = 0; r < 4; ++r) {
      const int qrow = qb + w * 16 + lq * 4 + r;
      xa[((size_t)(b * SQ + qrow)) * DMODEL + h * DK + nd * 16 + lr] =
          o[nd][r] * inv[r];
    }
}

// ---------------------------------------------------------------------------
extern "C" void kernel_launch(void *const *d_in, const int *in_sizes, int n_in,
                              void *d_out, int out_size, void *d_ws,
                              size_t ws_size, hipStream_t stream) {
  (void)in_sizes; (void)n_in; (void)out_size;
  const float *query = (const float *)d_in[0];
  const float *key_  = (const float *)d_in[1];
  const float *value = (const float *)d_in[2];
  const float *Wq = (const float *)d_in[3];
  const float *bq = (const float *)d_in[4];
  const float *Wk = (const float *)d_in[5];
  const float *bk = (const float *)d_in[6];
  const float *Wv = (const float *)d_in[7];
  const float *bv = (const float *)d_in[8];
  const float *Wo = (const float *)d_in[9];
  const float *bo = (const float *)d_in[10];
  float *out = (float *)d_out;

  const size_t MB = (size_t)1 << 20;
  if (ws_size < 40 * MB) return;

  char *ws = (char *)d_ws;
  ushort *qp  = (ushort *)(ws);            // 8 MB bf16 [B*S][512]
  ushort *kp  = (ushort *)(ws + 8 * MB);   // 8 MB bf16 [B*S][512]
  ushort *vpt = (ushort *)(ws + 16 * MB);  // 8 MB bf16 [B*512 n][2048 s]
  float  *xa  = (float *)(ws + 24 * MB);   // 16 MB fp32 [B*S][512]

  dim3 gg(DMODEL / BN, (BATCH * SQ) / BM);
  proj_gemm_t<1><<<gg, 256, 0, stream>>>(query, Wq, bq, (void *)qp);
  proj_gemm_t<1><<<gg, 256, 0, stream>>>(key_, Wk, bk, (void *)kp);
  proj_gemm_t<2><<<gg, 256, 0, stream>>>(value, Wv, bv, (void *)vpt);

  attn_mfma<<<dim3(SQ / 64, NH, BATCH), 256, 0, stream>>>(qp, kp, vpt, xa);

  proj_gemm_t<0><<<gg, 256, 0, stream>>>(xa, Wo, bo, out);
}

// Round 4
// 721.639 us; speedup vs baseline: 3.4845x; 1.1002x over previous
//
#include <hip/hip_runtime.h>
#include <stdint.h>

#define BATCH  4
#define SQ     2048
#define DMODEL 512
#define NH     8
#define DK     64

typedef __attribute__((ext_vector_type(8))) short short8;
typedef __attribute__((ext_vector_type(4))) float f32x4;

// ---------------- threefry2x32 (JAX-compatible, 20 rounds) ----------------
struct TFK { uint32_t a, b; };
constexpr uint32_t rotl_ce(uint32_t x, int d) {
  return (x << d) | (x >> (32 - d));
}
constexpr TFK tf_ce(uint32_t k0, uint32_t k1, uint32_t x0, uint32_t x1) {
  const uint32_t ks[3] = {k0, k1, k0 ^ k1 ^ 0x1BD11BDAu};
  const int rot[2][4] = {{13, 15, 26, 6}, {17, 29, 16, 24}};
  x0 += k0; x1 += k1;
  for (int c = 0; c < 5; ++c) {
    for (int j = 0; j < 4; ++j) {
      x0 += x1; x1 = rotl_ce(x1, rot[c & 1][j]); x1 ^= x0;
    }
    x0 += ks[(c + 1) % 3];
    x1 += ks[(c + 2) % 3] + (uint32_t)(c + 1);
  }
  return TFK{x0, x1};
}
constexpr TFK SPK = tf_ce(0u, 42u, 0u, 1u);  // fold_in(key(42), 1)
constexpr TFK DPK = tf_ce(0u, 42u, 0u, 2u);  // fold_in(key(42), 2)

template <uint32_t K0, uint32_t K1>
__device__ __forceinline__ uint32_t tf_bits(uint32_t ctr) {
  constexpr uint32_t KS2 = K0 ^ K1 ^ 0x1BD11BDAu;
  uint32_t x0 = K0;
  uint32_t x1 = K1 + ctr;
#define RND(d) { x0 += x1; x1 = __builtin_amdgcn_alignbit(x1, x1, 32 - (d)); x1 ^= x0; }
  RND(13) RND(15) RND(26) RND(6)
  x0 += K1; x1 += KS2 + 1u;
  RND(17) RND(29) RND(16) RND(24)
  x0 += KS2; x1 += K0 + 2u;
  RND(13) RND(15) RND(26) RND(6)
  x0 += K0; x1 += K1 + 3u;
  RND(17) RND(29) RND(16) RND(24)
  x0 += K1; x1 += KS2 + 4u;
  RND(13) RND(15) RND(26) RND(6)
  x0 += KS2; x1 += K0 + 5u;
#undef RND
  return x0 ^ x1;
}

#define SP_THR 0x80000200u
#define DP_THR 0x1999A200u

__device__ __forceinline__ ushort f2bf_rne(float f) {
  uint32_t u = __float_as_uint(f);
  return (ushort)((u + 0x7fffu + ((u >> 16) & 1u)) >> 16);
}
__device__ __forceinline__ float bf2f(ushort h) {
  return __uint_as_float((uint32_t)h << 16);
}

// ---------------- hi/lo split prep kernels ---------------------------------
// x = hi + lo with hi = RNE-bf16(x), lo = RNE-bf16(x - hi) (x - hi exact).
__device__ __forceinline__ void split4(const float *__restrict__ src,
                                       ushort *__restrict__ dh,
                                       ushort *__restrict__ dl, size_t base) {
  float4 x = *(const float4 *)(src + base);
  uint32_t h[4], lo[4];
#pragma unroll
  for (int i = 0; i < 4; ++i) {
    float xi = ((const float *)&x)[i];
    ushort hh = f2bf_rne(xi);
    h[i] = hh;
    lo[i] = f2bf_rne(xi - bf2f(hh));
  }
  uint2 ph, pl;
  ph.x = h[0] | (h[1] << 16);  ph.y = h[2] | (h[3] << 16);
  pl.x = lo[0] | (lo[1] << 16); pl.y = lo[2] | (lo[3] << 16);
  *(uint2 *)(dh + base) = ph;
  *(uint2 *)(dl + base) = pl;
}

__global__ __launch_bounds__(256) void split_inputs_k(
    const float *__restrict__ q, const float *__restrict__ k,
    const float *__restrict__ v, ushort *__restrict__ qh,
    ushort *__restrict__ ql, ushort *__restrict__ kh, ushort *__restrict__ kl,
    ushort *__restrict__ vh, ushort *__restrict__ vl) {
  const float *src = blockIdx.y == 0 ? q : (blockIdx.y == 1 ? k : v);
  ushort *dh = blockIdx.y == 0 ? qh : (blockIdx.y == 1 ? kh : vh);
  ushort *dl = blockIdx.y == 0 ? ql : (blockIdx.y == 1 ? kl : vl);
  const size_t base = ((size_t)blockIdx.x * 256 + threadIdx.x) * 4;
  split4(src, dh, dl, base);
}

__global__ __launch_bounds__(256) void split_w_k(
    const float *__restrict__ w0, const float *__restrict__ w1,
    const float *__restrict__ w2, const float *__restrict__ w3,
    ushort *__restrict__ h0, ushort *__restrict__ l0, ushort *__restrict__ h1,
    ushort *__restrict__ l1, ushort *__restrict__ h2, ushort *__restrict__ l2,
    ushort *__restrict__ h3, ushort *__restrict__ l3) {
  const int y = blockIdx.y;
  const float *src = y == 0 ? w0 : (y == 1 ? w1 : (y == 2 ? w2 : w3));
  ushort *dh = y == 0 ? h0 : (y == 1 ? h1 : (y == 2 ? h2 : h3));
  ushort *dl = y == 0 ? l0 : (y == 1 ? l1 : (y == 2 ? l2 : l3));
  const size_t base = ((size_t)blockIdx.x * 256 + threadIdx.x) * 4;
  split4(src, dh, dl, base);
}

// ---------------- hi/lo bf16 MFMA GEMM: D = A @ B^T (+bias) ----------------
// A: [AM][512] hi/lo bf16 row-major.  B: [BN][512] hi/lo bf16 row-major.
// D[i][j] = sum_k A[i][k] B[j][k], computed AhBh + AhBl + AlBh (~fp32-exact).
// Block: 128(Arows) x 64(Brows), 4 waves, wave = 32x64 (2x4 16x16 frags).
// MODE 0: fp32 out Y[i*512+j], bias[j].   MODE 1: bf16 out, bias[j].
// MODE 2: bf16 out TRANSPOSED vpt[((j>>11)*512 + i)*2048 + (j&2047)], bias[i]
//         (used as A=Wv, B=value -> writes per-head V^T directly).
template <int MODE>
__global__ __launch_bounds__(256) void proj_mfma(
    const ushort *__restrict__ Ah, const ushort *__restrict__ Al,
    const ushort *__restrict__ Bh, const ushort *__restrict__ Bl,
    const float *__restrict__ bias, void *__restrict__ Yv) {
  const int tid = threadIdx.x;
  const int w = tid >> 6, l = tid & 63;
  const int lr = l & 15, lq = l >> 4;
  const int am = blockIdx.y * 128 + w * 32;
  const int bn = blockIdx.x * 64;
  f32x4 acc[2][4];
#pragma unroll
  for (int i = 0; i < 2; ++i)
#pragma unroll
    for (int j = 0; j < 4; ++j) acc[i][j] = (f32x4){0.f, 0.f, 0.f, 0.f};

#pragma unroll 2
  for (int k0 = 0; k0 < DMODEL; k0 += 32) {
    short8 ah[2], al[2], bh[4], bl[4];
#pragma unroll
    for (int mf = 0; mf < 2; ++mf) {
      const size_t off = (size_t)(am + mf * 16 + lr) * DMODEL + k0 + lq * 8;
      ah[mf] = *(const short8 *)(Ah + off);
      al[mf] = *(const short8 *)(Al + off);
    }
#pragma unroll
    for (int nf = 0; nf < 4; ++nf) {
      const size_t off = (size_t)(bn + nf * 16 + lr) * DMODEL + k0 + lq * 8;
      bh[nf] = *(const short8 *)(Bh + off);
      bl[nf] = *(const short8 *)(Bl + off);
    }
#pragma unroll
    for (int mf = 0; mf < 2; ++mf)
#pragma unroll
      for (int nf = 0; nf < 4; ++nf) {
        acc[mf][nf] = __builtin_amdgcn_mfma_f32_16x16x32_bf16(
            ah[mf], bh[nf], acc[mf][nf], 0, 0, 0);
        acc[mf][nf] = __builtin_amdgcn_mfma_f32_16x16x32_bf16(
            ah[mf], bl[nf], acc[mf][nf], 0, 0, 0);
        acc[mf][nf] = __builtin_amdgcn_mfma_f32_16x16x32_bf16(
            al[mf], bh[nf], acc[mf][nf], 0, 0, 0);
      }
  }

#pragma unroll
  for (int mf = 0; mf < 2; ++mf)
#pragma unroll
    for (int nf = 0; nf < 4; ++nf) {
      if (MODE == 0) {
        float *Y = (float *)Yv;
        const int gn = bn + nf * 16 + lr;
        const float bb = bias[gn];
#pragma unroll
        for (int r = 0; r < 4; ++r) {
          const int gm = am + mf * 16 + lq * 4 + r;
          Y[(size_t)gm * DMODEL + gn] = acc[mf][nf][r] + bb;
        }
      } else if (MODE == 1) {
        ushort *Y = (ushort *)Yv;
        const int gn = bn + nf * 16 + lr;
        const float bb = bias[gn];
#pragma unroll
        for (int r = 0; r < 4; ++r) {
          const int gm = am + mf * 16 + lq * 4 + r;
          Y[(size_t)gm * DMODEL + gn] = f2bf_rne(acc[mf][nf][r] + bb);
        }
      } else {
        ushort *Y = (ushort *)Yv;
        const int gm2 = bn + nf * 16 + lr;        // value row (0..8191)
        const int bcol = gm2 >> 11, scol = gm2 & 2047;
#pragma unroll
        for (int r = 0; r < 4; ++r) {
          const int gn2 = am + mf * 16 + lq * 4 + r;  // V feature (0..511)
          Y[((size_t)(bcol * DMODEL + gn2)) * SQ + scol] =
              f2bf_rne(acc[mf][nf][r] + bias[gn2]);
        }
      }
    }
}

// ---------------- MFMA attention with fused mask generation -----------------
__global__ __launch_bounds__(256, 2) void attn_mfma(
    const ushort *__restrict__ qp, const ushort *__restrict__ kp,
    const ushort *__restrict__ vpt, ushort *__restrict__ xah,
    ushort *__restrict__ xal) {
  __shared__ __align__(16) uint8_t lds[24576];
  uint8_t *Ks = lds;
  uint8_t *Vt = lds + 8192;
  const int b = blockIdx.z, h = blockIdx.y;
  const int qb = blockIdx.x * 64;
  const int tid = threadIdx.x;
  const int w = tid >> 6, l = tid & 63;
  const int lr = l & 15, lq = l >> 4;
  uint8_t *Ps = lds + 16384 + w * 2048;
  const int bh = b * NH + h;

  short8 qf[2];
  {
    const int qrow = qb + w * 16 + lr;
    const ushort *qrowp = qp + ((size_t)(b * SQ + qrow)) * DMODEL + h * DK;
    qf[0] = *(const short8 *)(qrowp + lq * 8);
    qf[1] = *(const short8 *)(qrowp + 32 + lq * 8);
  }
  f32x4 o[4];
  f32x4 lacc;
#pragma unroll
  for (int nd = 0; nd < 4; ++nd) o[nd] = (f32x4){0.f, 0.f, 0.f, 0.f};
  lacc = (f32x4){0.f, 0.f, 0.f, 0.f};

  uint32_t rowflat[4];
#pragma unroll
  for (int r = 0; r < 4; ++r)
    rowflat[r] = ((uint32_t)(bh * SQ + qb + w * 16 + lq * 4 + r)) << 11;

  for (int kv = 0; kv < SQ; kv += 64) {
    __syncthreads();
    {
      const int row = tid >> 2;
      const int c0 = (tid & 3) * 2;
      const int sw = (row & 7) << 4;
      const ushort *ksrc =
          kp + ((size_t)(b * SQ + kv + row)) * DMODEL + h * DK + c0 * 8;
      uint4 d0 = *(const uint4 *)ksrc;
      uint4 d1 = *(const uint4 *)(ksrc + 8);
      *(uint4 *)(Ks + ((row * 128 + c0 * 16) ^ sw)) = d0;
      *(uint4 *)(Ks + ((row * 128 + (c0 + 1) * 16) ^ sw)) = d1;
      const ushort *vsrc = vpt + ((size_t)(bh * DK + row)) * SQ + kv + c0 * 8;
      uint4 e0 = *(const uint4 *)vsrc;
      uint4 e1 = *(const uint4 *)(vsrc + 8);
      *(uint4 *)(Vt + ((row * 128 + c0 * 16) ^ sw)) = e0;
      *(uint4 *)(Vt + ((row * 128 + (c0 + 1) * 16) ^ sw)) = e1;
    }
    __syncthreads();

    f32x4 s[4];
#pragma unroll
    for (int ni = 0; ni < 4; ++ni) s[ni] = (f32x4){0.f, 0.f, 0.f, 0.f};
#pragma unroll
    for (int ni = 0; ni < 4; ++ni) {
      const int krow = ni * 16 + lr;
      const int sw = (krow & 7) << 4;
#pragma unroll
      for (int kf = 0; kf < 2; ++kf) {
        short8 kb =
            *(const short8 *)(Ks + ((krow * 128 + kf * 64 + lq * 16) ^ sw));
        s[ni] = __builtin_amdgcn_mfma_f32_16x16x32_bf16(qf[kf], kb, s[ni], 0, 0, 0);
      }
    }

#pragma unroll
    for (int ni = 0; ni < 4; ++ni) {
#pragma unroll
      for (int r = 0; r < 4; ++r) {
        const uint32_t ctr = rowflat[r] + (uint32_t)(kv + ni * 16 + lr);
        const bool keep_s = tf_bits<SPK.a, SPK.b>(ctr) >= SP_THR;
        const bool keep_d = tf_bits<DPK.a, DPK.b>(ctr) >= DP_THR;
        float e = __expf(s[ni][r] * 0.125f);
        float p = keep_s ? e : 0.0f;
        lacc[r] += p;
        float pd = keep_d ? p * (1.0f / 0.9f) : 0.0f;
        const int prow = lq * 4 + r;
        *(ushort *)(Ps + ((prow * 128 + (ni * 16 + lr) * 2) ^ ((prow & 7) << 4))) =
            f2bf_rne(pd);
      }
    }

#pragma unroll
    for (int kf = 0; kf < 2; ++kf) {
      short8 pa = *(const short8 *)(Ps +
                                    ((lr * 128 + kf * 64 + lq * 16) ^ ((lr & 7) << 4)));
#pragma unroll
      for (int nd = 0; nd < 4; ++nd) {
        const int vrow = nd * 16 + lr;
        short8 vb = *(const short8 *)(Vt + ((vrow * 128 + kf * 64 + lq * 16) ^
                                            ((vrow & 7) << 4)));
        o[nd] = __builtin_amdgcn_mfma_f32_16x16x32_bf16(pa, vb, o[nd], 0, 0, 0);
      }
    }
  }

  float inv[4];
#pragma unroll
  for (int r = 0; r < 4; ++r) {
    float t = lacc[r];
    t += __shfl_xor(t, 1);
    t += __shfl_xor(t, 2);
    t += __shfl_xor(t, 4);
    t += __shfl_xor(t, 8);
    inv[r] = 1.0f / t;
  }
#pragma unroll
  for (int nd = 0; nd < 4; ++nd)
#pragma unroll
    for (int r = 0; r < 4; ++r) {
      const int qrow = qb + w * 16 + lq * 4 + r;
      const size_t idx =
          ((size_t)(b * SQ + qrow)) * DMODEL + h * DK + nd * 16 + lr;
      const float val = o[nd][r] * inv[r];
      const ushort hh = f2bf_rne(val);
      xah[idx] = hh;
      xal[idx] = f2bf_rne(val - bf2f(hh));
    }
}

// ---------------------------------------------------------------------------
extern "C" void kernel_launch(void *const *d_in, const int *in_sizes, int n_in,
                              void *d_out, int out_size, void *d_ws,
                              size_t ws_size, hipStream_t stream) {
  (void)in_sizes; (void)n_in; (void)out_size;
  const float *query = (const float *)d_in[0];
  const float *key_  = (const float *)d_in[1];
  const float *value = (const float *)d_in[2];
  const float *Wq = (const float *)d_in[3];
  const float *bq = (const float *)d_in[4];
  const float *Wk = (const float *)d_in[5];
  const float *bk = (const float *)d_in[6];
  const float *Wv = (const float *)d_in[7];
  const float *bv = (const float *)d_in[8];
  const float *Wo = (const float *)d_in[9];
  const float *bo = (const float *)d_in[10];
  float *out = (float *)d_out;

  const size_t MB = (size_t)1 << 20;
  if (ws_size < 92 * MB) return;

  char *ws = (char *)d_ws;
  ushort *qih = (ushort *)(ws);             // 8 MB each
  ushort *qil = (ushort *)(ws + 8 * MB);
  ushort *kih = (ushort *)(ws + 16 * MB);
  ushort *kil = (ushort *)(ws + 24 * MB);
  ushort *vih = (ushort *)(ws + 32 * MB);
  ushort *vil = (ushort *)(ws + 40 * MB);
  ushort *Wqh = (ushort *)(ws + 48 * MB);   // 0.5 MB each
  ushort *Wql = (ushort *)(ws + 48 * MB + 512 * 1024);
  ushort *Wkh = (ushort *)(ws + 49 * MB);
  ushort *Wkl = (ushort *)(ws + 49 * MB + 512 * 1024);
  ushort *Wvh = (ushort *)(ws + 50 * MB);
  ushort *Wvl = (ushort *)(ws + 50 * MB + 512 * 1024);
  ushort *Woh = (ushort *)(ws + 51 * MB);
  ushort *Wol = (ushort *)(ws + 51 * MB + 512 * 1024);
  ushort *qp  = (ushort *)(ws + 52 * MB);   // 8 MB bf16 [B*S][512]
  ushort *kp  = (ushort *)(ws + 60 * MB);   // 8 MB
  ushort *vpt = (ushort *)(ws + 68 * MB);   // 8 MB bf16 [B*512][2048]
  ushort *xah = (ushort *)(ws + 76 * MB);   // 8 MB
  ushort *xal = (ushort *)(ws + 84 * MB);   // 8 MB

  split_inputs_k<<<dim3(4096, 3), 256, 0, stream>>>(query, key_, value, qih,
                                                    qil, kih, kil, vih, vil);
  split_w_k<<<dim3(256, 4), 256, 0, stream>>>(Wq, Wk, Wv, Wo, Wqh, Wql, Wkh,
                                              Wkl, Wvh, Wvl, Woh, Wol);

  proj_mfma<1><<<dim3(8, 64), 256, 0, stream>>>(qih, qil, Wqh, Wql, bq, qp);
  proj_mfma<1><<<dim3(8, 64), 256, 0, stream>>>(kih, kil, Wkh, Wkl, bk, kp);
  proj_mfma<2><<<dim3(128, 4), 256, 0, stream>>>(Wvh, Wvl, vih, vil, bv, vpt);

  attn_mfma<<<dim3(SQ / 64, NH, BATCH), 256, 0, stream>>>(qp, kp, vpt, xah,
                                                          xal);

  proj_mfma<0><<<dim3(8, 64), 256, 0, stream>>>(xah, xal, Woh, Wol, bo, out);
}

// Round 5
// 715.451 us; speedup vs baseline: 3.5146x; 1.0086x over previous
//
#include <hip/hip_runtime.h>
#include <stdint.h>

#define BATCH  4
#define SQ     2048
#define DMODEL 512
#define NH     8
#define DK     64

typedef __attribute__((ext_vector_type(8))) short short8;
typedef __attribute__((ext_vector_type(4))) float f32x4;

// ---------------- threefry2x32 (JAX-compatible, 20 rounds) ----------------
struct TFK { uint32_t a, b; };
constexpr uint32_t rotl_ce(uint32_t x, int d) {
  return (x << d) | (x >> (32 - d));
}
constexpr TFK tf_ce(uint32_t k0, uint32_t k1, uint32_t x0, uint32_t x1) {
  const uint32_t ks[3] = {k0, k1, k0 ^ k1 ^ 0x1BD11BDAu};
  const int rot[2][4] = {{13, 15, 26, 6}, {17, 29, 16, 24}};
  x0 += k0; x1 += k1;
  for (int c = 0; c < 5; ++c) {
    for (int j = 0; j < 4; ++j) {
      x0 += x1; x1 = rotl_ce(x1, rot[c & 1][j]); x1 ^= x0;
    }
    x0 += ks[(c + 1) % 3];
    x1 += ks[(c + 2) % 3] + (uint32_t)(c + 1);
  }
  return TFK{x0, x1};
}
constexpr TFK SPK = tf_ce(0u, 42u, 0u, 1u);  // fold_in(key(42), 1)
constexpr TFK DPK = tf_ce(0u, 42u, 0u, 2u);  // fold_in(key(42), 2)

#define SP_THR 0x80000200u
#define DP_THR 0x1999A200u

// Key-schedule constants passed as KERNEL ARGS so they live in SGPRs
// (no 32-bit literals in the hot loop; enables v_add3_u32 folding).
// layout: c[0]=k0 c[1]=k1 c[2]=ks2+1 c[3]=k0+2 c[4]=k1+3 c[5]=ks2+4
//         c[6]=k0+5 c[7]=ks2
struct TfArgs {
  uint32_t sp[8];
  uint32_t dp[8];
  uint32_t sp_thr, dp_thr;
};

__device__ __forceinline__ void tf_round(uint32_t &x0, uint32_t &x1, int d) {
  x0 += x1;
  x1 = __builtin_amdgcn_alignbit(x1, x1, 32 - d);
  x1 ^= x0;
}
// group head: x1 += injx1; x0 = x0 + injx0 + x1 (v_add3); then rot/xor + 3 rounds
__device__ __forceinline__ void tf_grp(uint32_t &x0, uint32_t &x1,
                                       uint32_t injx1, uint32_t injx0, int d0,
                                       int d1, int d2, int d3) {
  x1 += injx1;
  x0 = x0 + injx0 + x1;
  x1 = __builtin_amdgcn_alignbit(x1, x1, 32 - d0);
  x1 ^= x0;
  tf_round(x0, x1, d1);
  tf_round(x0, x1, d2);
  tf_round(x0, x1, d3);
}
__device__ __forceinline__ uint32_t tf_rt(const uint32_t *__restrict__ c,
                                          uint32_t ctr) {
  uint32_t x1 = c[1] + ctr;
  uint32_t x0 = c[0] + x1;                       // round1 head (x0=k0, +=x1)
  x1 = __builtin_amdgcn_alignbit(x1, x1, 19);    // rot 13
  x1 ^= x0;
  tf_round(x0, x1, 15);
  tf_round(x0, x1, 26);
  tf_round(x0, x1, 6);
  tf_grp(x0, x1, c[2], c[1], 17, 29, 16, 24);    // inj1: x0+=k1,  x1+=ks2+1
  tf_grp(x0, x1, c[3], c[7], 13, 15, 26, 6);     // inj2: x0+=ks2, x1+=k0+2
  tf_grp(x0, x1, c[4], c[0], 17, 29, 16, 24);    // inj3: x0+=k0,  x1+=k1+3
  tf_grp(x0, x1, c[5], c[1], 13, 15, 26, 6);     // inj4: x0+=k1,  x1+=ks2+4
  return (x0 + c[7]) ^ (x1 + c[6]);              // inj5 + combine
}

__device__ __forceinline__ ushort f2bf_rne(float f) {
  uint32_t u = __float_as_uint(f);
  return (ushort)((u + 0x7fffu + ((u >> 16) & 1u)) >> 16);
}
__device__ __forceinline__ float bf2f(ushort h) {
  return __uint_as_float((uint32_t)h << 16);
}
__device__ __forceinline__ float exp_scaled(float s) {  // exp(s/8)
#if __has_builtin(__builtin_amdgcn_exp2f)
  return __builtin_amdgcn_exp2f(s * 0.18033688011112042f);  // 0.125*log2(e)
#else
  return __expf(s * 0.125f);
#endif
}

// ---------------- hi/lo split prep kernels ---------------------------------
__device__ __forceinline__ void split4(const float *__restrict__ src,
                                       ushort *__restrict__ dh,
                                       ushort *__restrict__ dl, size_t base) {
  float4 x = *(const float4 *)(src + base);
  uint32_t h[4], lo[4];
#pragma unroll
  for (int i = 0; i < 4; ++i) {
    float xi = ((const float *)&x)[i];
    ushort hh = f2bf_rne(xi);
    h[i] = hh;
    lo[i] = f2bf_rne(xi - bf2f(hh));
  }
  uint2 ph, pl;
  ph.x = h[0] | (h[1] << 16);  ph.y = h[2] | (h[3] << 16);
  pl.x = lo[0] | (lo[1] << 16); pl.y = lo[2] | (lo[3] << 16);
  *(uint2 *)(dh + base) = ph;
  *(uint2 *)(dl + base) = pl;
}

__global__ __launch_bounds__(256) void split_inputs_k(
    const float *__restrict__ q, const float *__restrict__ k,
    const float *__restrict__ v, ushort *__restrict__ qh,
    ushort *__restrict__ ql, ushort *__restrict__ kh, ushort *__restrict__ kl,
    ushort *__restrict__ vh, ushort *__restrict__ vl) {
  const float *src = blockIdx.y == 0 ? q : (blockIdx.y == 1 ? k : v);
  ushort *dh = blockIdx.y == 0 ? qh : (blockIdx.y == 1 ? kh : vh);
  ushort *dl = blockIdx.y == 0 ? ql : (blockIdx.y == 1 ? kl : vl);
  const size_t base = ((size_t)blockIdx.x * 256 + threadIdx.x) * 4;
  split4(src, dh, dl, base);
}

__global__ __launch_bounds__(256) void split_w_k(
    const float *__restrict__ w0, const float *__restrict__ w1,
    const float *__restrict__ w2, const float *__restrict__ w3,
    ushort *__restrict__ h0, ushort *__restrict__ l0, ushort *__restrict__ h1,
    ushort *__restrict__ l1, ushort *__restrict__ h2, ushort *__restrict__ l2,
    ushort *__restrict__ h3, ushort *__restrict__ l3) {
  const int y = blockIdx.y;
  const float *src = y == 0 ? w0 : (y == 1 ? w1 : (y == 2 ? w2 : w3));
  ushort *dh = y == 0 ? h0 : (y == 1 ? h1 : (y == 2 ? h2 : h3));
  ushort *dl = y == 0 ? l0 : (y == 1 ? l1 : (y == 2 ? l2 : l3));
  const size_t base = ((size_t)blockIdx.x * 256 + threadIdx.x) * 4;
  split4(src, dh, dl, base);
}

// ---------------- hi/lo bf16 MFMA GEMM: D = A @ B^T (+bias) ----------------
// MODE 0: fp32 out, bias[j].  MODE 1: bf16 out, bias[j].
// MODE 2: bf16 out transposed per-head vpt, bias[i]; coalesced via LDS.
template <int MODE>
__global__ __launch_bounds__(256) void proj_mfma(
    const ushort *__restrict__ Ah, const ushort *__restrict__ Al,
    const ushort *__restrict__ Bh, const ushort *__restrict__ Bl,
    const float *__restrict__ bias, void *__restrict__ Yv) {
  __shared__ ushort Tt[MODE == 2 ? 128 * 72 : 1];
  const int tid = threadIdx.x;
  const int w = tid >> 6, l = tid & 63;
  const int lr = l & 15, lq = l >> 4;
  const int am = blockIdx.y * 128 + w * 32;
  const int bn = blockIdx.x * 64;
  f32x4 acc[2][4];
#pragma unroll
  for (int i = 0; i < 2; ++i)
#pragma unroll
    for (int j = 0; j < 4; ++j) acc[i][j] = (f32x4){0.f, 0.f, 0.f, 0.f};

#pragma unroll 2
  for (int k0 = 0; k0 < DMODEL; k0 += 32) {
    short8 ah[2], al[2], bh[4], bl[4];
#pragma unroll
    for (int mf = 0; mf < 2; ++mf) {
      const size_t off = (size_t)(am + mf * 16 + lr) * DMODEL + k0 + lq * 8;
      ah[mf] = *(const short8 *)(Ah + off);
      al[mf] = *(const short8 *)(Al + off);
    }
#pragma unroll
    for (int nf = 0; nf < 4; ++nf) {
      const size_t off = (size_t)(bn + nf * 16 + lr) * DMODEL + k0 + lq * 8;
      bh[nf] = *(const short8 *)(Bh + off);
      bl[nf] = *(const short8 *)(Bl + off);
    }
#pragma unroll
    for (int mf = 0; mf < 2; ++mf)
#pragma unroll
      for (int nf = 0; nf < 4; ++nf) {
        acc[mf][nf] = __builtin_amdgcn_mfma_f32_16x16x32_bf16(
            ah[mf], bh[nf], acc[mf][nf], 0, 0, 0);
        acc[mf][nf] = __builtin_amdgcn_mfma_f32_16x16x32_bf16(
            ah[mf], bl[nf], acc[mf][nf], 0, 0, 0);
        acc[mf][nf] = __builtin_amdgcn_mfma_f32_16x16x32_bf16(
            al[mf], bh[nf], acc[mf][nf], 0, 0, 0);
      }
  }

  if (MODE == 2) {
    // stage bf16 block tile [128 feat][64 valrow] (pad 72) then coalesced out
#pragma unroll
    for (int mf = 0; mf < 2; ++mf)
#pragma unroll
      for (int nf = 0; nf < 4; ++nf) {
        const int gn2 = am + mf * 16 + lq * 4;  // feature base
#pragma unroll
        for (int r = 0; r < 4; ++r) {
          const int featl = (w * 32 + mf * 16 + lq * 4 + r);
          Tt[featl * 72 + nf * 16 + lr] =
              f2bf_rne(acc[mf][nf][r] + bias[gn2 + r]);
        }
      }
    __syncthreads();
    ushort *Y = (ushort *)Yv;
    const int feat = tid >> 1, half = tid & 1;
    const int gfeat = blockIdx.y * 128 + feat;
    const int bcol = bn >> 11, scol = (bn & 2047) + half * 32;
    ushort *dst = Y + ((size_t)(bcol * DMODEL + gfeat)) * SQ + scol;
    const ushort *srcp = &Tt[feat * 72 + half * 32];
#pragma unroll
    for (int j = 0; j < 4; ++j)
      *(uint4 *)(dst + j * 8) = *(const uint4 *)(srcp + j * 8);
    return;
  }

#pragma unroll
  for (int mf = 0; mf < 2; ++mf)
#pragma unroll
    for (int nf = 0; nf < 4; ++nf) {
      const int gn = bn + nf * 16 + lr;
      const float bb = bias[gn];
      if (MODE == 0) {
        float *Y = (float *)Yv;
#pragma unroll
        for (int r = 0; r < 4; ++r) {
          const int gm = am + mf * 16 + lq * 4 + r;
          Y[(size_t)gm * DMODEL + gn] = acc[mf][nf][r] + bb;
        }
      } else {
        ushort *Y = (ushort *)Yv;
#pragma unroll
        for (int r = 0; r < 4; ++r) {
          const int gm = am + mf * 16 + lq * 4 + r;
          Y[(size_t)gm * DMODEL + gn] = f2bf_rne(acc[mf][nf][r] + bb);
        }
      }
    }
}

// ---------------- MFMA attention, fused masks, double-buffered staging ------
__global__ __launch_bounds__(256, 2) void attn_mfma(
    const ushort *__restrict__ qp, const ushort *__restrict__ kp,
    const ushort *__restrict__ vpt, ushort *__restrict__ xah,
    ushort *__restrict__ xal, TfArgs ta) {
  // LDS: K buf0 [0,8K) buf1 [8K,16K); V buf0 [16K,24K) buf1 [24K,32K);
  //      Ps [32K,40K) per-wave 2KB
  __shared__ __align__(16) uint8_t lds[40960];
  const int b = blockIdx.z, h = blockIdx.y;
  const int qb = blockIdx.x * 64;
  const int tid = threadIdx.x;
  const int w = tid >> 6, l = tid & 63;
  const int lr = l & 15, lq = l >> 4;
  uint8_t *Ps = lds + 32768 + w * 2048;
  const int bh = b * NH + h;

  short8 qf[2];
  {
    const int qrow = qb + w * 16 + lr;
    const ushort *qrowp = qp + ((size_t)(b * SQ + qrow)) * DMODEL + h * DK;
    qf[0] = *(const short8 *)(qrowp + lq * 8);
    qf[1] = *(const short8 *)(qrowp + 32 + lq * 8);
  }
  f32x4 o[4];
  f32x4 lacc;
#pragma unroll
  for (int nd = 0; nd < 4; ++nd) o[nd] = (f32x4){0.f, 0.f, 0.f, 0.f};
  lacc = (f32x4){0.f, 0.f, 0.f, 0.f};

  uint32_t rowflat[4];
#pragma unroll
  for (int r = 0; r < 4; ++r)
    rowflat[r] = ((uint32_t)(bh * SQ + qb + w * 16 + lq * 4 + r)) << 11;

  // staging addresses (tile-relative)
  const int srow = tid >> 2;
  const int sc0 = (tid & 3) * 2;
  const int ssw = (srow & 7) << 4;
  const ushort *kbase =
      kp + ((size_t)(b * SQ) + srow) * DMODEL + h * DK + sc0 * 8;
  const ushort *vbase = vpt + ((size_t)(bh * DK + srow)) * SQ + sc0 * 8;
  const int la0 = (srow * 128 + sc0 * 16) ^ ssw;
  const int la1 = (srow * 128 + (sc0 + 1) * 16) ^ ssw;

  uint4 kr0, kr1, vr0, vr1;
#define ISSUE(kv_)                                            \
  {                                                           \
    const ushort *ks_ = kbase + (size_t)(kv_)*DMODEL;         \
    kr0 = *(const uint4 *)ks_;                                \
    kr1 = *(const uint4 *)(ks_ + 8);                          \
    const ushort *vs_ = vbase + (kv_);                        \
    vr0 = *(const uint4 *)vs_;                                \
    vr1 = *(const uint4 *)(vs_ + 8);                          \
  }
#define STORE(buf_)                                           \
  {                                                           \
    uint8_t *Kb_ = lds + (buf_)*8192;                         \
    uint8_t *Vb_ = lds + 16384 + (buf_)*8192;                 \
    *(uint4 *)(Kb_ + la0) = kr0;                              \
    *(uint4 *)(Kb_ + la1) = kr1;                              \
    *(uint4 *)(Vb_ + la0) = vr0;                              \
    *(uint4 *)(Vb_ + la1) = vr1;                              \
  }

  ISSUE(0)
  STORE(0)
  __syncthreads();

  for (int kv = 0; kv < SQ; kv += 64) {
    const int cur = (kv >> 6) & 1;
    uint8_t *Ks = lds + cur * 8192;
    uint8_t *Vt = lds + 16384 + cur * 8192;
    const bool more = (kv + 64) < SQ;
    if (more) ISSUE(kv + 64)

    // QK^T: 16 q x 64 keys per wave
    f32x4 s[4];
#pragma unroll
    for (int ni = 0; ni < 4; ++ni) s[ni] = (f32x4){0.f, 0.f, 0.f, 0.f};
#pragma unroll
    for (int ni = 0; ni < 4; ++ni) {
      const int krow = ni * 16 + lr;
      const int sw = (krow & 7) << 4;
#pragma unroll
      for (int kf = 0; kf < 2; ++kf) {
        short8 kb =
            *(const short8 *)(Ks + ((krow * 128 + kf * 64 + lq * 16) ^ sw));
        s[ni] =
            __builtin_amdgcn_mfma_f32_16x16x32_bf16(qf[kf], kb, s[ni], 0, 0, 0);
      }
    }

    // fused threefry masks + softmax numerator + dropout -> P in LDS
    const uint32_t colbase = (uint32_t)(kv + lr);
#pragma unroll
    for (int ni = 0; ni < 4; ++ni) {
#pragma unroll
      for (int r = 0; r < 4; ++r) {
        const uint32_t ctr = rowflat[r] + colbase + (uint32_t)(ni * 16);
        const bool keep_s = tf_rt(ta.sp, ctr) >= ta.sp_thr;
        const bool keep_d = tf_rt(ta.dp, ctr) >= ta.dp_thr;
        float e = exp_scaled(s[ni][r]);
        float p = keep_s ? e : 0.0f;
        lacc[r] += p;
        float pd = keep_d ? p * (1.0f / 0.9f) : 0.0f;
        const int prow = lq * 4 + r;
        *(ushort *)(Ps +
                    ((prow * 128 + (ni * 16 + lr) * 2) ^ ((prow & 7) << 4))) =
            f2bf_rne(pd);
      }
    }

    // PV: out[16 q][64 d] += P(16x64) * V(64x64)
#pragma unroll
    for (int kf = 0; kf < 2; ++kf) {
      short8 pa = *(const short8 *)(Ps + ((lr * 128 + kf * 64 + lq * 16) ^
                                          ((lr & 7) << 4)));
#pragma unroll
      for (int nd = 0; nd < 4; ++nd) {
        const int vrow = nd * 16 + lr;
        short8 vb = *(const short8 *)(Vt + ((vrow * 128 + kf * 64 + lq * 16) ^
                                            ((vrow & 7) << 4)));
        o[nd] = __builtin_amdgcn_mfma_f32_16x16x32_bf16(pa, vb, o[nd], 0, 0, 0);
      }
    }

    if (more) STORE(cur ^ 1)
    __syncthreads();
  }
#undef ISSUE
#undef STORE

  float inv[4];
#pragma unroll
  for (int r = 0; r < 4; ++r) {
    float t = lacc[r];
    t += __shfl_xor(t, 1);
    t += __shfl_xor(t, 2);
    t += __shfl_xor(t, 4);
    t += __shfl_xor(t, 8);
    inv[r] = 1.0f / t;
  }
#pragma unroll
  for (int nd = 0; nd < 4; ++nd)
#pragma unroll
    for (int r = 0; r < 4; ++r) {
      const int qrow = qb + w * 16 + lq * 4 + r;
      const size_t idx =
          ((size_t)(b * SQ + qrow)) * DMODEL + h * DK + nd * 16 + lr;
      const float val = o[nd][r] * inv[r];
      const ushort hh = f2bf_rne(val);
      xah[idx] = hh;
      xal[idx] = f2bf_rne(val - bf2f(hh));
    }
}

// ---------------------------------------------------------------------------
extern "C" void kernel_launch(void *const *d_in, const int *in_sizes, int n_in,
                              void *d_out, int out_size, void *d_ws,
                              size_t ws_size, hipStream_t stream) {
  (void)in_sizes; (void)n_in; (void)out_size;
  const float *query = (const float *)d_in[0];
  const float *key_  = (const float *)d_in[1];
  const float *value = (const float *)d_in[2];
  const float *Wq = (const float *)d_in[3];
  const float *bq = (const float *)d_in[4];
  const float *Wk = (const float *)d_in[5];
  const float *bk = (const float *)d_in[6];
  const float *Wv = (const float *)d_in[7];
  const float *bv = (const float *)d_in[8];
  const float *Wo = (const float *)d_in[9];
  const float *bo = (const float *)d_in[10];
  float *out = (float *)d_out;

  const size_t MB = (size_t)1 << 20;
  if (ws_size < 92 * MB) return;

  char *ws = (char *)d_ws;
  ushort *qih = (ushort *)(ws);
  ushort *qil = (ushort *)(ws + 8 * MB);
  ushort *kih = (ushort *)(ws + 16 * MB);
  ushort *kil = (ushort *)(ws + 24 * MB);
  ushort *vih = (ushort *)(ws + 32 * MB);
  ushort *vil = (ushort *)(ws + 40 * MB);
  ushort *Wqh = (ushort *)(ws + 48 * MB);
  ushort *Wql = (ushort *)(ws + 48 * MB + 512 * 1024);
  ushort *Wkh = (ushort *)(ws + 49 * MB);
  ushort *Wkl = (ushort *)(ws + 49 * MB + 512 * 1024);
  ushort *Wvh = (ushort *)(ws + 50 * MB);
  ushort *Wvl = (ushort *)(ws + 50 * MB + 512 * 1024);
  ushort *Woh = (ushort *)(ws + 51 * MB);
  ushort *Wol = (ushort *)(ws + 51 * MB + 512 * 1024);
  ushort *qp  = (ushort *)(ws + 52 * MB);
  ushort *kp  = (ushort *)(ws + 60 * MB);
  ushort *vpt = (ushort *)(ws + 68 * MB);
  ushort *xah = (ushort *)(ws + 76 * MB);
  ushort *xal = (ushort *)(ws + 84 * MB);

  constexpr uint32_t KS2s = SPK.a ^ SPK.b ^ 0x1BD11BDAu;
  constexpr uint32_t KS2d = DPK.a ^ DPK.b ^ 0x1BD11BDAu;
  TfArgs ta = {
      {SPK.a, SPK.b, KS2s + 1u, SPK.a + 2u, SPK.b + 3u, KS2s + 4u, SPK.a + 5u,
       KS2s},
      {DPK.a, DPK.b, KS2d + 1u, DPK.a + 2u, DPK.b + 3u, KS2d + 4u, DPK.a + 5u,
       KS2d},
      SP_THR, DP_THR};

  split_inputs_k<<<dim3(4096, 3), 256, 0, stream>>>(query, key_, value, qih,
                                                    qil, kih, kil, vih, vil);
  split_w_k<<<dim3(256, 4), 256, 0, stream>>>(Wq, Wk, Wv, Wo, Wqh, Wql, Wkh,
                                              Wkl, Wvh, Wvl, Woh, Wol);

  proj_mfma<1><<<dim3(8, 64), 256, 0, stream>>>(qih, qil, Wqh, Wql, bq, qp);
  proj_mfma<1><<<dim3(8, 64), 256, 0, stream>>>(kih, kil, Wkh, Wkl, bk, kp);
  proj_mfma<2><<<dim3(128, 4), 256, 0, stream>>>(Wvh, Wvl, vih, vil, bv, vpt);

  attn_mfma<<<dim3(SQ / 64, NH, BATCH), 256, 0, stream>>>(qp, kp, vpt, xah,
                                                          xal, ta);

  proj_mfma<0><<<dim3(8, 64), 256, 0, stream>>>(xah, xal, Woh, Wol, bo, out);
}